// Round 2
// 2152.428 us; speedup vs baseline: 3.3511x; 3.3511x over previous
//
#include <hip/hip_runtime.h>

typedef __bf16 bf16;
typedef __bf16 bf16x8 __attribute__((ext_vector_type(8)));
typedef __bf16 bf16x4 __attribute__((ext_vector_type(4)));
typedef float f32x4 __attribute__((ext_vector_type(4)));

// ---------------- workspace layout (bytes) ----------------
// Persistent: RT, XP, MASK, FLAGS, RING. KT/XE are prep-only and overlay the ring.
static constexpr size_t SZ_RT   = 2ull*3072*1024*2;          // rec^T bf16 [2][3072][1024]
static constexpr size_t SZ_XP   = 2ull*16384*3072*2;         // xp bf16 [d][j][t][g][b][16] (slabs reused for f32 out-partials)
static constexpr size_t SZ_MASK = 16384ull*4;                // mask f32 [t][b]
static constexpr size_t SLOT    = 2ull*8192*16;              // one ring slot = [d][8192 chunks of 16B]
static constexpr size_t OFF_RT   = 0;
static constexpr size_t OFF_XP   = OFF_RT + SZ_RT;
static constexpr size_t OFF_MASK = OFF_XP + SZ_XP;
static constexpr size_t OFF_BAR  = OFF_MASK + SZ_MASK;       // 2 KB flag region (flags[128])
static constexpr size_t OFF_RING = OFF_BAR + 2048;           // 257 slots (write-once per call)
static constexpr size_t OFF_KT   = OFF_RING;                 // prep-only (dead before ring use)
static constexpr size_t OFF_XE   = OFF_RING + 2ull*3072*1024*2;

// ---------------- prep kernels ----------------
// Runs AFTER xp_gemm (overlays KT): zero ring slot 0 (initial h) + flag region.
__global__ void zero_ws_k(char* ws) {
  size_t i = (size_t)blockIdx.x*256 + threadIdx.x;
  if (i < SLOT/16)                  ((uint4*)(ws + OFF_RING))[i] = make_uint4(0u,0u,0u,0u);
  else if (i < SLOT/16 + 128)       ((uint4*)(ws + OFF_BAR))[i - SLOT/16] = make_uint4(0u,0u,0u,0u);
}

// f32 [1024][3072] -> bf16 [3072][1024] (n-major) for MFMA B-fragment loads
__global__ void transpose_cast_k(const float* kf, const float* kb,
                                 const float* rf, const float* rb, char* ws) {
  __shared__ float tile[32][33];
  const int mat = blockIdx.z;
  const float* src = (mat==0)?kf:(mat==1)?kb:(mat==2)?rf:rb;
  bf16* dst = (bf16*)(ws + ((mat<2)?OFF_KT:OFF_RT)) + (size_t)(mat&1)*3072*1024;
  const int k0 = blockIdx.x*32, n0 = blockIdx.y*32;
  const int r = threadIdx.x >> 5, c = threadIdx.x & 31;
  for (int rr = r; rr < 32; rr += 8)
    tile[rr][c] = src[(size_t)(k0+rr)*3072 + n0 + c];
  __syncthreads();
  const int rn = threadIdx.x >> 3, kq = threadIdx.x & 7;
  bf16x4 v;
  #pragma unroll
  for (int ii = 0; ii < 4; ++ii) v[ii] = (bf16)tile[kq*4+ii][rn];
  *(bf16x4*)(dst + (size_t)(n0+rn)*1024 + k0 + kq*4) = v;
}

__global__ void gather_xe_k(const int* x, const float* emb, char* ws) {
  size_t c = (size_t)blockIdx.x*256 + threadIdx.x;   // 16384*128 chunks of 8
  int rowid = (int)(c >> 7); int u8 = (int)(c & 127);
  int t = rowid >> 6, b = rowid & 63;
  int tok = x[b*256 + t];
  const float* e = emb + (size_t)tok*1024 + u8*8;
  float4 a  = *(const float4*)e;
  float4 b2 = *(const float4*)(e+4);
  bf16x8 o;
  o[0]=(bf16)a.x;  o[1]=(bf16)a.y;  o[2]=(bf16)a.z;  o[3]=(bf16)a.w;
  o[4]=(bf16)b2.x; o[5]=(bf16)b2.y; o[6]=(bf16)b2.z; o[7]=(bf16)b2.w;
  *(bf16x8*)((bf16*)(ws+OFF_XE) + (size_t)rowid*1024 + u8*8) = o;
}

__global__ void make_mask_k(const int* x, char* ws) {
  int tid = blockIdx.x*256 + threadIdx.x;            // t*64+b
  int t = tid >> 6, b = tid & 63;
  ((float*)(ws+OFF_MASK))[tid] = (x[b*256+t] != 0) ? 1.0f : 0.0f;
}

__device__ __forceinline__ void async16(void* lds, const void* g) {
  __builtin_amdgcn_global_load_lds((const __attribute__((address_space(1))) unsigned int*)g,
                                   (__attribute__((address_space(3))) unsigned int*)lds,
                                   16, 0, 0);
}

// ---------------- xp = xe @ kernel + b_i (both dirs), 128x128 tile ----------------
__global__ __launch_bounds__(256) void xp_gemm_k(const float* bias_f, const float* bias_b, char* ws) {
  __shared__ __align__(16) char smem[16384];         // As 128x32, Bs 128x32 bf16
  const int tid = threadIdx.x, w = tid>>6, l = tid&63;
  const int m0 = blockIdx.x*128, n0 = blockIdx.y*128, d = blockIdx.z;
  const bf16* xe = (const bf16*)(ws + OFF_XE);
  const bf16* Bt = (const bf16*)(ws + OFF_KT) + (size_t)d*3072*1024;
  const float* bias = d ? bias_b : bias_f;           // row 0 = b_i
  const int wm = (w>>1)*64, wn = (w&1)*64;
  const f32x4 fzero = {0.f,0.f,0.f,0.f};
  f32x4 acc[4][4];
  #pragma unroll
  for (int i=0;i<4;++i)
    #pragma unroll
    for (int jj=0;jj<4;++jj) acc[i][jj] = fzero;
  for (int k0 = 0; k0 < 1024; k0 += 32) {
    #pragma unroll
    for (int it = 0; it < 2; ++it) {
      int cc = w*128 + it*64 + l;                    // 0..511
      int row = cc>>2, kp = cc&3;
      async16(smem        + (size_t)(w*128 + it*64)*16, xe + (size_t)(m0+row)*1024 + k0 + kp*8);
      async16(smem + 8192 + (size_t)(w*128 + it*64)*16, Bt + (size_t)(n0+row)*1024 + k0 + kp*8);
    }
    __builtin_amdgcn_s_waitcnt(0);
    __syncthreads();
    const bf16* As = (const bf16*)smem;
    const bf16* Bs = (const bf16*)(smem + 8192);
    bf16x8 bfr[4];
    #pragma unroll
    for (int nt=0;nt<4;++nt)
      bfr[nt] = *(const bf16x8*)(Bs + (wn + nt*16 + (l&15))*32 + (l>>4)*8);
    #pragma unroll
    for (int mt=0;mt<4;++mt) {
      bf16x8 af = *(const bf16x8*)(As + (wm + mt*16 + (l&15))*32 + (l>>4)*8);
      #pragma unroll
      for (int nt=0;nt<4;++nt)
        acc[mt][nt] = __builtin_amdgcn_mfma_f32_16x16x32_bf16(af, bfr[nt], acc[mt][nt], 0,0,0);
    }
    __syncthreads();
  }
  bf16* xp = (bf16*)(ws + OFF_XP);
  #pragma unroll
  for (int nt=0;nt<4;++nt) {
    int n = n0 + wn + nt*16 + (l&15);
    float bv = bias[n];
    int g = n>>10, jj = (n>>4)&63, u = n&15;
    #pragma unroll
    for (int mt=0;mt<4;++mt) {
      #pragma unroll
      for (int r2=0;r2<4;++r2) {
        int m = m0 + wm + mt*16 + (l>>4)*4 + r2;
        int t = m>>6, b = m&63;
        float val = acc[mt][nt][r2] + bv;
        xp[((((size_t)(d*64+jj)*256 + t)*3 + g)*64 + b)*16 + u] = (bf16)val;
      }
    }
  }
}

// ---------------- persistent GRU scan ----------------
// 128 WGs: wg = d*64 + j (j = 16-unit block). Store-only flag sync:
// writer stores its h fragment (agent scope), drains vmcnt, sets flags[wg]=step+1.
// Readers poll only their own direction's 64 flags, then load A-fragments
// straight from the ring (global->VGPR; no LDS staging). K-split partials go
// through per-wave LDS slabs (plain stores), summed at read time.
// Per-step f32 outputs are written into the dead xp slab just consumed;
// a final kernel sums fwd+bwd partials into out (no atomics anywhere).
__global__ __launch_bounds__(256, 1) void gru_scan_k(char* ws,
                                                     const float* bias_f, const float* bias_b) {
  __shared__ __align__(16) float parts[4*3*64*16];    // [w][g][b][u16] partials (48 KB)
  const int wg = blockIdx.x;
  const int d = wg >> 6, j = wg & 63;
  const int tid = threadIdx.x, w = tid >> 6, l = tid & 63;
  const bf16* rT    = (const bf16*)(ws + OFF_RT) + (size_t)d*3072*1024;
  const char* xp    = (const char*)(ws + OFF_XP);
  const float* mask = (const float*)(ws + OFF_MASK);
  char* ring = ws + OFF_RING;
  unsigned* flags = (unsigned*)(ws + OFF_BAR);
  const float* bias = d ? bias_b : bias_f;
  const f32x4 fzero = {0.f,0.f,0.f,0.f};

  // epilogue mapping: tid -> (batch b, unit-quad uq) ; owns units j*16+uq*4..+4
  const int b = tid >> 2, uq = tid & 3;

  // b_r in registers
  f32x4 br[3];
  #pragma unroll
  for (int g = 0; g < 3; ++g)
    br[g] = *(const f32x4*)(bias + 3072 + g*1024 + j*16 + uq*4);

  // rec_kernel B-fragments pinned in VGPRs (per-wave K-slice: 8 ktiles)
  const int kt0 = w*8;
  bf16x8 Breg[24];
  #pragma unroll
  for (int g = 0; g < 3; ++g)
    #pragma unroll
    for (int kk = 0; kk < 8; ++kk)
      Breg[g*8+kk] = *(const bf16x8*)(rT + (size_t)(g*1024 + j*16 + (l&15))*1024
                                         + (kt0+kk)*32 + (l>>4)*8);

  // f32 h state in registers (this thread's 4 units)
  float hold[4] = {0.f, 0.f, 0.f, 0.f};

  // ring chunk address for this thread's h fragment (8B half-chunk)
  const int wq = (j&1)*2 + (uq>>1);
  const int chunk = ((j>>1)*4 + (b>>4))*64 + ((b & 15) | (wq << 4));
  const int coff = chunk*16 + (uq&1)*8;

  // step-0 xp/mask prefetch
  bf16x4 xz_c, xr_c, xh_c; float m_c;
  {
    const int t0 = d ? 255 : 0;
    const char* xpt = xp + ((size_t)(d*64 + j)*256 + t0)*6144;
    xz_c = *(const bf16x4*)(xpt +        tid*8);
    xr_c = *(const bf16x4*)(xpt + 2048 + tid*8);
    xh_c = *(const bf16x4*)(xpt + 4096 + tid*8);
    m_c  = mask[t0*64 + b];
  }

  for (int step = 0; step < 256; ++step) {
    const int t = d ? (255 - step) : step;
    // ---- wait for own direction's h fragments of ring slot `step`
    if (step) {
      unsigned v = __hip_atomic_load(&flags[d*64 + l], __ATOMIC_RELAXED, __HIP_MEMORY_SCOPE_AGENT);
      while (!__all((int)(v >= (unsigned)step))) {
        __builtin_amdgcn_s_sleep(2);
        v = __hip_atomic_load(&flags[d*64 + l], __ATOMIC_RELAXED, __HIP_MEMORY_SCOPE_AGENT);
      }
    }
    const char* hsrc = ring + (size_t)step*SLOT + (size_t)d*(SLOT/2);
    // ---- GEMM: A-fragments straight from ring (double-buffered over kt)
    f32x4 acc[4][3];
    #pragma unroll
    for (int mt=0;mt<4;++mt) { acc[mt][0]=fzero; acc[mt][1]=fzero; acc[mt][2]=fzero; }
    bf16x8 aP[4], aN[4];
    #pragma unroll
    for (int mt=0;mt<4;++mt)
      aP[mt] = *(const bf16x8*)(hsrc + ((size_t)(kt0*4 + mt)*64 + l)*16);
    #pragma unroll
    for (int kk = 0; kk < 8; ++kk) {
      if (kk < 7) {
        #pragma unroll
        for (int mt=0;mt<4;++mt)
          aN[mt] = *(const bf16x8*)(hsrc + ((size_t)((kt0+kk+1)*4 + mt)*64 + l)*16);
      }
      #pragma unroll
      for (int mt = 0; mt < 4; ++mt) {
        acc[mt][0] = __builtin_amdgcn_mfma_f32_16x16x32_bf16(aP[mt], Breg[0*8+kk], acc[mt][0],0,0,0);
        acc[mt][1] = __builtin_amdgcn_mfma_f32_16x16x32_bf16(aP[mt], Breg[1*8+kk], acc[mt][1],0,0,0);
        acc[mt][2] = __builtin_amdgcn_mfma_f32_16x16x32_bf16(aP[mt], Breg[2*8+kk], acc[mt][2],0,0,0);
      }
      if (kk < 7) {
        #pragma unroll
        for (int mt=0;mt<4;++mt) aP[mt] = aN[mt];
      }
    }
    // ---- per-wave partial slabs (plain stores, no atomics)
    #pragma unroll
    for (int mt = 0; mt < 4; ++mt)
      #pragma unroll
      for (int g = 0; g < 3; ++g)
        #pragma unroll
        for (int r2 = 0; r2 < 4; ++r2)
          parts[((w*3+g)*64 + mt*16 + (l>>4)*4 + r2)*16 + (l&15)] = acc[mt][g][r2];
    __syncthreads();
    // ---- epilogue on all 256 threads: sum 4 wave-partials + bias, gate math
    f32x4 rec0 = br[0], rec1 = br[1], rec2 = br[2];
    #pragma unroll
    for (int w2 = 0; w2 < 4; ++w2) {
      rec0 += *(const f32x4*)&parts[(w2*3+0)*1024 + tid*4];
      rec1 += *(const f32x4*)&parts[(w2*3+1)*1024 + tid*4];
      rec2 += *(const f32x4*)&parts[(w2*3+2)*1024 + tid*4];
    }
    f32x4 hv;
    #pragma unroll
    for (int i = 0; i < 4; ++i) {
      float z = 1.f/(1.f + __expf(-((float)xz_c[i] + rec0[i])));
      float r = 1.f/(1.f + __expf(-((float)xr_c[i] + rec1[i])));
      float pre = (float)xh_c[i] + r*rec2[i];
      pre = fminf(fmaxf(pre, -15.f), 15.f);
      float e2 = __expf(-2.f*pre);
      float hh = (1.f - e2)/(1.f + e2);
      float hn = z*hold[i] + (1.f - z)*hh;
      float ho = (m_c != 0.f) ? hn : hold[i];
      hold[i] = ho;
      hv[i] = ho;
    }
    // ---- publish next h fragment + flag (skip on final step)
    if (step < 255) {
      union { bf16 h4[4]; unsigned long long q; } pk;
      #pragma unroll
      for (int i = 0; i < 4; ++i) pk.h4[i] = (bf16)hv[i];
      char* hdst = ring + (size_t)(step+1)*SLOT + (size_t)d*(SLOT/2);
      __hip_atomic_store((unsigned long long*)(hdst + coff), pk.q,
                         __ATOMIC_RELAXED, __HIP_MEMORY_SCOPE_AGENT);
      __builtin_amdgcn_s_waitcnt(0);          // h stores at coherence point
      __syncthreads();                        // all waves drained
      if (tid == 0)
        __hip_atomic_store(&flags[wg], (unsigned)(step+1),
                           __ATOMIC_RELAXED, __HIP_MEMORY_SCOPE_AGENT);
    }
    // ---- f32 out-partial into the dead xp slab (off critical path, plain store)
    {
      float* slab = (float*)(ws + OFF_XP + ((size_t)(d*64 + j)*256 + t)*6144);
      *(f32x4*)(slab + tid*4) = hv;
    }
    // ---- prefetch next xp/mask (after flag; hides under next poll)
    if (step < 255) {
      const int tn = d ? (254 - step) : (step + 1);
      const char* xpn = xp + ((size_t)(d*64 + j)*256 + tn)*6144;
      xz_c = *(const bf16x4*)(xpn +        tid*8);
      xr_c = *(const bf16x4*)(xpn + 2048 + tid*8);
      xh_c = *(const bf16x4*)(xpn + 4096 + tid*8);
      m_c  = mask[tn*64 + b];
    }
  }
}

// ---------------- final: out = fwd partial + bwd partial ----------------
__global__ void add_out_k(const char* ws, float* out) {
  size_t i = (size_t)blockIdx.x*256 + threadIdx.x;   // (b,t,j,uq) f32x4 units
  int uqq = (int)(i & 3), j = (int)((i>>2) & 63), t = (int)((i>>8) & 255), b = (int)(i >> 16);
  const float* pf = (const float*)(ws + OFF_XP + ((size_t)(     j)*256 + t)*6144);
  const float* pb = (const float*)(ws + OFF_XP + ((size_t)(64 + j)*256 + t)*6144);
  f32x4 a = *(const f32x4*)(pf + b*16 + uqq*4);
  f32x4 c = *(const f32x4*)(pb + b*16 + uqq*4);
  *(f32x4*)(out + ((size_t)b*256 + t)*1024 + j*16 + uqq*4) = a + c;
}

// ---------------- launch ----------------
extern "C" void kernel_launch(void* const* d_in, const int* in_sizes, int n_in,
                              void* d_out, int out_size, void* d_ws, size_t ws_size,
                              hipStream_t stream) {
  (void)in_sizes; (void)n_in; (void)out_size; (void)ws_size;
  const int*   x   = (const int*)d_in[0];
  const float* emb = (const float*)d_in[1];
  const float* kf  = (const float*)d_in[2];
  const float* rf  = (const float*)d_in[3];
  const float* bf_ = (const float*)d_in[4];
  const float* kb  = (const float*)d_in[5];
  const float* rb  = (const float*)d_in[6];
  const float* bb  = (const float*)d_in[7];
  char* ws = (char*)d_ws;
  float* out = (float*)d_out;
  transpose_cast_k<<<dim3(32,96,4), 256, 0, stream>>>(kf, kb, rf, rb, ws);
  gather_xe_k<<<8192, 256, 0, stream>>>(x, emb, ws);
  make_mask_k<<<64, 256, 0, stream>>>(x, ws);
  xp_gemm_k<<<dim3(128,24,2), 256, 0, stream>>>(bf_, bb, ws);
  zero_ws_k<<<65, 256, 0, stream>>>(ws);   // after xp_gemm: ring slot0 overlays dead KT
  gru_scan_k<<<128, 256, 0, stream>>>(ws, bf_, bb);
  add_out_k<<<16384, 256, 0, stream>>>(ws, out);
}

// Round 3
// 2132.170 us; speedup vs baseline: 3.3830x; 1.0095x over previous
//
#include <hip/hip_runtime.h>

typedef __bf16 bf16;
typedef __bf16 bf16x8 __attribute__((ext_vector_type(8)));
typedef __bf16 bf16x4 __attribute__((ext_vector_type(4)));
typedef float f32x4 __attribute__((ext_vector_type(4)));

// ---------------- workspace layout (bytes) ----------------
// Persistent: RT, XP, MASK, FLAGS, RING. KT/XE are prep-only and overlay the ring.
static constexpr size_t SZ_RT   = 2ull*3072*1024*2;          // rec^T bf16 [2][3072][1024]
static constexpr size_t SZ_XP   = 2ull*16384*3072*2;         // xp bf16 [d][j][t][g][b][16] (slabs reused for f32 out-partials)
static constexpr size_t SZ_MASK = 16384ull*4;                // mask f32 [t][b]
static constexpr size_t SLOT    = 2ull*8192*16;              // one ring slot = [d][8192 chunks of 16B]
static constexpr size_t OFF_RT   = 0;
static constexpr size_t OFF_XP   = OFF_RT + SZ_RT;
static constexpr size_t OFF_MASK = OFF_XP + SZ_XP;
static constexpr size_t OFF_BAR  = OFF_MASK + SZ_MASK;       // 2 KB flag region: u32 flags[2][64][4] (d,j,wave)
static constexpr size_t OFF_RING = OFF_BAR + 2048;           // 257 slots (write-once per call)
static constexpr size_t OFF_KT   = OFF_RING;                 // prep-only (dead before ring use)
static constexpr size_t OFF_XE   = OFF_RING + 2ull*3072*1024*2;

// ---------------- prep kernels ----------------
// Runs AFTER xp_gemm (overlays KT): zero ring slot 0 (initial h) + flag region.
__global__ void zero_ws_k(char* ws) {
  size_t i = (size_t)blockIdx.x*256 + threadIdx.x;
  if (i < SLOT/16)                  ((uint4*)(ws + OFF_RING))[i] = make_uint4(0u,0u,0u,0u);
  else if (i < SLOT/16 + 128)       ((uint4*)(ws + OFF_BAR))[i - SLOT/16] = make_uint4(0u,0u,0u,0u);
}

// f32 [1024][3072] -> bf16 [3072][1024] (n-major) for MFMA B-fragment loads
__global__ void transpose_cast_k(const float* kf, const float* kb,
                                 const float* rf, const float* rb, char* ws) {
  __shared__ float tile[32][33];
  const int mat = blockIdx.z;
  const float* src = (mat==0)?kf:(mat==1)?kb:(mat==2)?rf:rb;
  bf16* dst = (bf16*)(ws + ((mat<2)?OFF_KT:OFF_RT)) + (size_t)(mat&1)*3072*1024;
  const int k0 = blockIdx.x*32, n0 = blockIdx.y*32;
  const int r = threadIdx.x >> 5, c = threadIdx.x & 31;
  for (int rr = r; rr < 32; rr += 8)
    tile[rr][c] = src[(size_t)(k0+rr)*3072 + n0 + c];
  __syncthreads();
  const int rn = threadIdx.x >> 3, kq = threadIdx.x & 7;
  bf16x4 v;
  #pragma unroll
  for (int ii = 0; ii < 4; ++ii) v[ii] = (bf16)tile[kq*4+ii][rn];
  *(bf16x4*)(dst + (size_t)(n0+rn)*1024 + k0 + kq*4) = v;
}

__global__ void gather_xe_k(const int* x, const float* emb, char* ws) {
  size_t c = (size_t)blockIdx.x*256 + threadIdx.x;   // 16384*128 chunks of 8
  int rowid = (int)(c >> 7); int u8 = (int)(c & 127);
  int t = rowid >> 6, b = rowid & 63;
  int tok = x[b*256 + t];
  const float* e = emb + (size_t)tok*1024 + u8*8;
  float4 a  = *(const float4*)e;
  float4 b2 = *(const float4*)(e+4);
  bf16x8 o;
  o[0]=(bf16)a.x;  o[1]=(bf16)a.y;  o[2]=(bf16)a.z;  o[3]=(bf16)a.w;
  o[4]=(bf16)b2.x; o[5]=(bf16)b2.y; o[6]=(bf16)b2.z; o[7]=(bf16)b2.w;
  *(bf16x8*)((bf16*)(ws+OFF_XE) + (size_t)rowid*1024 + u8*8) = o;
}

__global__ void make_mask_k(const int* x, char* ws) {
  int tid = blockIdx.x*256 + threadIdx.x;            // t*64+b
  int t = tid >> 6, b = tid & 63;
  ((float*)(ws+OFF_MASK))[tid] = (x[b*256+t] != 0) ? 1.0f : 0.0f;
}

__device__ __forceinline__ void async16(void* lds, const void* g) {
  __builtin_amdgcn_global_load_lds((const __attribute__((address_space(1))) unsigned int*)g,
                                   (__attribute__((address_space(3))) unsigned int*)lds,
                                   16, 0, 0);
}

// ---------------- xp = xe @ kernel + b_i (both dirs), 128x128 tile ----------------
__global__ __launch_bounds__(256) void xp_gemm_k(const float* bias_f, const float* bias_b, char* ws) {
  __shared__ __align__(16) char smem[16384];         // As 128x32, Bs 128x32 bf16
  const int tid = threadIdx.x, w = tid>>6, l = tid&63;
  const int m0 = blockIdx.x*128, n0 = blockIdx.y*128, d = blockIdx.z;
  const bf16* xe = (const bf16*)(ws + OFF_XE);
  const bf16* Bt = (const bf16*)(ws + OFF_KT) + (size_t)d*3072*1024;
  const float* bias = d ? bias_b : bias_f;           // row 0 = b_i
  const int wm = (w>>1)*64, wn = (w&1)*64;
  const f32x4 fzero = {0.f,0.f,0.f,0.f};
  f32x4 acc[4][4];
  #pragma unroll
  for (int i=0;i<4;++i)
    #pragma unroll
    for (int jj=0;jj<4;++jj) acc[i][jj] = fzero;
  for (int k0 = 0; k0 < 1024; k0 += 32) {
    #pragma unroll
    for (int it = 0; it < 2; ++it) {
      int cc = w*128 + it*64 + l;                    // 0..511
      int row = cc>>2, kp = cc&3;
      async16(smem        + (size_t)(w*128 + it*64)*16, xe + (size_t)(m0+row)*1024 + k0 + kp*8);
      async16(smem + 8192 + (size_t)(w*128 + it*64)*16, Bt + (size_t)(n0+row)*1024 + k0 + kp*8);
    }
    __builtin_amdgcn_s_waitcnt(0);
    __syncthreads();
    const bf16* As = (const bf16*)smem;
    const bf16* Bs = (const bf16*)(smem + 8192);
    bf16x8 bfr[4];
    #pragma unroll
    for (int nt=0;nt<4;++nt)
      bfr[nt] = *(const bf16x8*)(Bs + (wn + nt*16 + (l&15))*32 + (l>>4)*8);
    #pragma unroll
    for (int mt=0;mt<4;++mt) {
      bf16x8 af = *(const bf16x8*)(As + (wm + mt*16 + (l&15))*32 + (l>>4)*8);
      #pragma unroll
      for (int nt=0;nt<4;++nt)
        acc[mt][nt] = __builtin_amdgcn_mfma_f32_16x16x32_bf16(af, bfr[nt], acc[mt][nt], 0,0,0);
    }
    __syncthreads();
  }
  bf16* xp = (bf16*)(ws + OFF_XP);
  #pragma unroll
  for (int nt=0;nt<4;++nt) {
    int n = n0 + wn + nt*16 + (l&15);
    float bv = bias[n];
    int g = n>>10, jj = (n>>4)&63, u = n&15;
    #pragma unroll
    for (int mt=0;mt<4;++mt) {
      #pragma unroll
      for (int r2=0;r2<4;++r2) {
        int m = m0 + wm + mt*16 + (l>>4)*4 + r2;
        int t = m>>6, b = m&63;
        float val = acc[mt][nt][r2] + bv;
        xp[((((size_t)(d*64+jj)*256 + t)*3 + g)*64 + b)*16 + u] = (bf16)val;
      }
    }
  }
}

// ---------------- persistent GRU scan ----------------
// 128 WGs: wg = d*64 + j (j = 16-unit block). Per-WAVE store-only flag sync:
// producer wave w holds exactly the rows of chunk-group mt=w, so after its own
// 64 agent-scope 8B stores drain (per-wave vmcnt), it sets flags[d][j][w].
// Consumer wave w only needs h columns from producers j in [16w,16w+16) -> its
// 64 needed flags are contiguous: one lane-spread atomic load + __all.
// A-fragments load straight from the ring (global->VGPR). K-split partials go
// through double-buffered per-wave LDS slabs (row stride 20 f32: conflict-free),
// ONE __syncthreads per step. Outputs go to the dead xp slab; add_out_k sums.
__global__ __launch_bounds__(256, 1) void gru_scan_k(char* ws,
                                                     const float* bias_f, const float* bias_b) {
  // parts[buf][w][g][row 64][col 20] f32 (row stride 20 = 80B: 16B-aligned, bank-spread)
  __shared__ __align__(16) float parts[2*4*3*64*20];  // 120 KB
  const int wg = blockIdx.x;
  const int d = wg >> 6, j = wg & 63;
  const int tid = threadIdx.x, w = tid >> 6, l = tid & 63;
  const bf16* rT    = (const bf16*)(ws + OFF_RT) + (size_t)d*3072*1024;
  const char* xp    = (const char*)(ws + OFF_XP);
  const float* mask = (const float*)(ws + OFF_MASK);
  char* ring = ws + OFF_RING;
  unsigned* flags = (unsigned*)(ws + OFF_BAR);        // [d][j][wave] = d*256 + j*4 + w
  const float* bias = d ? bias_b : bias_f;
  const f32x4 fzero = {0.f,0.f,0.f,0.f};

  // epilogue mapping: tid -> (batch b, unit-quad uq) ; owns units j*16+uq*4..+4
  const int b = tid >> 2, uq = tid & 3;

  // b_r in registers
  f32x4 br[3];
  #pragma unroll
  for (int g = 0; g < 3; ++g)
    br[g] = *(const f32x4*)(bias + 3072 + g*1024 + j*16 + uq*4);

  // rec_kernel B-fragments pinned in VGPRs (per-wave K-slice: 8 ktiles)
  const int kt0 = w*8;
  bf16x8 Breg[24];
  #pragma unroll
  for (int g = 0; g < 3; ++g)
    #pragma unroll
    for (int kk = 0; kk < 8; ++kk)
      Breg[g*8+kk] = *(const bf16x8*)(rT + (size_t)(g*1024 + j*16 + (l&15))*1024
                                         + (kt0+kk)*32 + (l>>4)*8);

  // f32 h state in registers (this thread's 4 units)
  float hold[4] = {0.f, 0.f, 0.f, 0.f};

  // ring chunk address for this thread's h fragment (8B half-chunk)
  const int wq = (j&1)*2 + (uq>>1);
  const int chunk = ((j>>1)*4 + (b>>4))*64 + ((b & 15) | (wq << 4));
  const int coff = chunk*16 + (uq&1)*8;

  // poll index: wave w consumes producers j' in [16w,16w+16), all 4 waves
  // -> flags indices d*256 + [w*64 .. w*64+64) ; one per lane.
  const unsigned fidx = (unsigned)(d*256 + w*64 + l);

  // step-0 xp/mask prefetch
  bf16x4 xz_c, xr_c, xh_c; float m_c;
  {
    const int t0 = d ? 255 : 0;
    const char* xpt = xp + ((size_t)(d*64 + j)*256 + t0)*6144;
    xz_c = *(const bf16x4*)(xpt +        tid*8);
    xr_c = *(const bf16x4*)(xpt + 2048 + tid*8);
    xh_c = *(const bf16x4*)(xpt + 4096 + tid*8);
    m_c  = mask[t0*64 + b];
  }

  for (int step = 0; step < 256; ++step) {
    const int t = d ? (255 - step) : step;
    // ---- wait for this wave's producers (step 0 passes trivially: v>=0)
    {
      unsigned v = __hip_atomic_load(&flags[fidx], __ATOMIC_RELAXED, __HIP_MEMORY_SCOPE_AGENT);
      while (!__all((int)(v >= (unsigned)step))) {
        __builtin_amdgcn_s_sleep(2);
        v = __hip_atomic_load(&flags[fidx], __ATOMIC_RELAXED, __HIP_MEMORY_SCOPE_AGENT);
      }
    }
    const char* hsrc = ring + (size_t)step*SLOT + (size_t)d*(SLOT/2);
    // ---- GEMM: A-fragments straight from ring (double-buffered over kt)
    f32x4 acc[4][3];
    #pragma unroll
    for (int mt=0;mt<4;++mt) { acc[mt][0]=fzero; acc[mt][1]=fzero; acc[mt][2]=fzero; }
    bf16x8 aP[4], aN[4];
    #pragma unroll
    for (int mt=0;mt<4;++mt)
      aP[mt] = *(const bf16x8*)(hsrc + ((size_t)(kt0*4 + mt)*64 + l)*16);
    #pragma unroll
    for (int kk = 0; kk < 8; ++kk) {
      if (kk < 7) {
        #pragma unroll
        for (int mt=0;mt<4;++mt)
          aN[mt] = *(const bf16x8*)(hsrc + ((size_t)((kt0+kk+1)*4 + mt)*64 + l)*16);
      }
      #pragma unroll
      for (int mt = 0; mt < 4; ++mt) {
        acc[mt][0] = __builtin_amdgcn_mfma_f32_16x16x32_bf16(aP[mt], Breg[0*8+kk], acc[mt][0],0,0,0);
        acc[mt][1] = __builtin_amdgcn_mfma_f32_16x16x32_bf16(aP[mt], Breg[1*8+kk], acc[mt][1],0,0,0);
        acc[mt][2] = __builtin_amdgcn_mfma_f32_16x16x32_bf16(aP[mt], Breg[2*8+kk], acc[mt][2],0,0,0);
      }
      if (kk < 7) {
        #pragma unroll
        for (int mt=0;mt<4;++mt) aP[mt] = aN[mt];
      }
    }
    // ---- per-wave partial slabs (plain stores; stride-20 rows: 2-way max = free)
    {
      float* pw = parts + ((size_t)((step&1)*4 + w)*3)*1280;
      #pragma unroll
      for (int mt = 0; mt < 4; ++mt)
        #pragma unroll
        for (int g = 0; g < 3; ++g)
          #pragma unroll
          for (int r2 = 0; r2 < 4; ++r2)
            pw[g*1280 + (mt*16 + (l>>4)*4 + r2)*20 + (l&15)] = acc[mt][g][r2];
    }
    __syncthreads();    // single barrier per step (parts visibility; dbuf covers next write)
    // ---- epilogue on all 256 threads: sum 4 wave-partials + bias, gate math
    f32x4 rec0 = br[0], rec1 = br[1], rec2 = br[2];
    {
      const float* pb = parts + (size_t)(step&1)*4*3*1280 + b*20 + uq*4;
      #pragma unroll
      for (int w2 = 0; w2 < 4; ++w2) {
        rec0 += *(const f32x4*)(pb + (w2*3+0)*1280);
        rec1 += *(const f32x4*)(pb + (w2*3+1)*1280);
        rec2 += *(const f32x4*)(pb + (w2*3+2)*1280);
      }
    }
    f32x4 hv;
    #pragma unroll
    for (int i = 0; i < 4; ++i) {
      float z = 1.f/(1.f + __expf(-((float)xz_c[i] + rec0[i])));
      float r = 1.f/(1.f + __expf(-((float)xr_c[i] + rec1[i])));
      float pre = (float)xh_c[i] + r*rec2[i];
      pre = fminf(fmaxf(pre, -15.f), 15.f);
      float e2 = __expf(-2.f*pre);
      float hh = (1.f - e2)/(1.f + e2);
      float hn = z*hold[i] + (1.f - z)*hh;
      float ho = (m_c != 0.f) ? hn : hold[i];
      hold[i] = ho;
      hv[i] = ho;
    }
    // ---- publish next h fragment; per-wave drain + per-wave flag (no barrier)
    if (step < 255) {
      union { bf16 h4[4]; unsigned long long q; } pk;
      #pragma unroll
      for (int i = 0; i < 4; ++i) pk.h4[i] = (bf16)hv[i];
      char* hdst = ring + (size_t)(step+1)*SLOT + (size_t)d*(SLOT/2);
      __hip_atomic_store((unsigned long long*)(hdst + coff), pk.q,
                         __ATOMIC_RELAXED, __HIP_MEMORY_SCOPE_AGENT);
      __builtin_amdgcn_s_waitcnt(0);          // this wave's h stores at coherence point
      asm volatile("" ::: "memory");
      if ((tid & 63) == 0)
        __hip_atomic_store(&flags[d*256 + j*4 + w], (unsigned)(step+1),
                           __ATOMIC_RELAXED, __HIP_MEMORY_SCOPE_AGENT);
    }
    // ---- f32 out-partial into the dead xp slab (off critical path, plain store)
    {
      float* slab = (float*)(ws + OFF_XP + ((size_t)(d*64 + j)*256 + t)*6144);
      *(f32x4*)(slab + tid*4) = hv;
    }
    // ---- prefetch next xp/mask (after flag; hides under next poll)
    if (step < 255) {
      const int tn = d ? (254 - step) : (step + 1);
      const char* xpn = xp + ((size_t)(d*64 + j)*256 + tn)*6144;
      xz_c = *(const bf16x4*)(xpn +        tid*8);
      xr_c = *(const bf16x4*)(xpn + 2048 + tid*8);
      xh_c = *(const bf16x4*)(xpn + 4096 + tid*8);
      m_c  = mask[tn*64 + b];
    }
  }
}

// ---------------- final: out = fwd partial + bwd partial ----------------
__global__ void add_out_k(const char* ws, float* out) {
  size_t i = (size_t)blockIdx.x*256 + threadIdx.x;   // (b,t,j,uq) f32x4 units
  int uqq = (int)(i & 3), j = (int)((i>>2) & 63), t = (int)((i>>8) & 255), b = (int)(i >> 16);
  const float* pf = (const float*)(ws + OFF_XP + ((size_t)(     j)*256 + t)*6144);
  const float* pb = (const float*)(ws + OFF_XP + ((size_t)(64 + j)*256 + t)*6144);
  f32x4 a = *(const f32x4*)(pf + b*16 + uqq*4);
  f32x4 c = *(const f32x4*)(pb + b*16 + uqq*4);
  *(f32x4*)(out + ((size_t)b*256 + t)*1024 + j*16 + uqq*4) = a + c;
}

// ---------------- launch ----------------
extern "C" void kernel_launch(void* const* d_in, const int* in_sizes, int n_in,
                              void* d_out, int out_size, void* d_ws, size_t ws_size,
                              hipStream_t stream) {
  (void)in_sizes; (void)n_in; (void)out_size; (void)ws_size;
  const int*   x   = (const int*)d_in[0];
  const float* emb = (const float*)d_in[1];
  const float* kf  = (const float*)d_in[2];
  const float* rf  = (const float*)d_in[3];
  const float* bf_ = (const float*)d_in[4];
  const float* kb  = (const float*)d_in[5];
  const float* rb  = (const float*)d_in[6];
  const float* bb  = (const float*)d_in[7];
  char* ws = (char*)d_ws;
  float* out = (float*)d_out;
  transpose_cast_k<<<dim3(32,96,4), 256, 0, stream>>>(kf, kb, rf, rb, ws);
  gather_xe_k<<<8192, 256, 0, stream>>>(x, emb, ws);
  make_mask_k<<<64, 256, 0, stream>>>(x, ws);
  xp_gemm_k<<<dim3(128,24,2), 256, 0, stream>>>(bf_, bb, ws);
  zero_ws_k<<<65, 256, 0, stream>>>(ws);   // after xp_gemm: ring slot0 overlays dead KT
  gru_scan_k<<<128, 256, 0, stream>>>(ws, bf_, bb);
  add_out_k<<<16384, 256, 0, stream>>>(ws, out);
}